// Round 2
// baseline (292.713 us; speedup 1.0000x reference)
//
#include <hip/hip_runtime.h>

namespace {

constexpr int K = 32;             // last-axis length
constexpr int RPW = 64;           // rows per wave (= wavefront size)

// Wave-cooperative sparsemax: each wave stages 64 rows through a
// column-major XOR-swizzled LDS tile so all global accesses are
// lane-contiguous (fully coalesced), then each lane sorts its own row
// in registers.
__global__ __launch_bounds__(256, 4)
void sparsemax_kernel(const float* __restrict__ x, float* __restrict__ out,
                      int ntiles) {
  __shared__ float lds[4][RPW * K];  // 4 waves/block * 8 KiB = 32 KiB

  const int tid  = threadIdx.x;
  const int widx = tid >> 6;   // wave index in block
  const int l    = tid & 63;   // lane
  float* __restrict__ wl = lds[widx];

  const int wave_global = blockIdx.x * 4 + widx;
  const int wave_stride = gridDim.x * 4;

  const int a = l >> 3;  // 0..7 : sub-row selector
  const int b = l & 7;   // 0..7 : col4 selector

  for (int t = wave_global; t < ntiles; t += wave_stride) {
    // 512 float4 per 64x32 tile; lane-contiguous addressing.
    const size_t base_f4 = (size_t)t * (RPW * K / 4);
    const float4* __restrict__ xp =
        reinterpret_cast<const float4*>(x) + base_f4 + l;

    float4 v[8];
#pragma unroll
    for (int i = 0; i < 8; ++i) v[i] = xp[(size_t)i * 64];
    // v[i] holds row (8i + a), cols 4b..4b+3 of this tile.

    // Previous iteration's LDS reads must complete before overwrite.
    asm volatile("s_waitcnt lgkmcnt(0)" ::: "memory");

    // Column-major swizzled scatter: element (row r, col c) at c*64 + (r^c).
    // Bank = (r^c)%32 -> exactly 2 lanes/bank per instruction (free).
#pragma unroll
    for (int i = 0; i < 8; ++i) {
      const int r = 8 * i + a;
      const int c0 = 4 * b;
      wl[(c0 + 0) * 64 + (r ^ (c0 + 0))] = v[i].x;
      wl[(c0 + 1) * 64 + (r ^ (c0 + 1))] = v[i].y;
      wl[(c0 + 2) * 64 + (r ^ (c0 + 2))] = v[i].z;
      wl[(c0 + 3) * 64 + (r ^ (c0 + 3))] = v[i].w;
    }

    asm volatile("s_waitcnt lgkmcnt(0)" ::: "memory");

    // Lane l gathers its full row l (conflict-free: bank = (l^c)%32).
    float rr[K];
#pragma unroll
    for (int c = 0; c < K; ++c) rr[c] = wl[c * 64 + (l ^ c)];

    // Bitonic sort, descending. 240 compare-exchanges, all static indices.
#pragma unroll
    for (int kk = 2; kk <= K; kk <<= 1) {
#pragma unroll
      for (int j = kk >> 1; j > 0; j >>= 1) {
#pragma unroll
        for (int i = 0; i < K; ++i) {
          const int m = i ^ j;
          if (m > i) {
            const float p = rr[i], q = rr[m];
            const float mn = fminf(p, q);
            const float mx = fmaxf(p, q);
            if ((i & kk) == 0) { rr[i] = mx; rr[m] = mn; }
            else               { rr[i] = mn; rr[m] = mx; }
          }
        }
      }
    }

    // cumsum + support count: kz = #{ j : 1 + (j+1)*z_j - cumsum_j > 0 }.
    float csum = 0.0f;
    int kz = 0;
#pragma unroll
    for (int j = 0; j < K; ++j) {
      csum += rr[j];
      const float cond = 1.0f + (float)(j + 1) * rr[j] - csum;
      kz += (cond > 0.0f) ? 1 : 0;
      rr[j] = csum;  // rr now holds cumsum
    }

    // Gather cumsum[kz-1] with a static cndmask chain (no scratch).
    float csel = rr[K - 1];
#pragma unroll
    for (int j = 0; j < K; ++j) csel = (kz == j + 1) ? rr[j] : csel;

    const float tau = (csel - 1.0f) / (float)kz;

    // Epilogue: lane l holds tau for row l; v[i] still holds the original
    // inputs for row 8i+a. Fetch the needed taus cross-lane, store coalesced.
    float4* __restrict__ op = reinterpret_cast<float4*>(out) + base_f4 + l;
#pragma unroll
    for (int i = 0; i < 8; ++i) {
      const float taur = __shfl(tau, 8 * i + a);
      float4 o;
      o.x = fmaxf(v[i].x - taur, 0.0f);
      o.y = fmaxf(v[i].y - taur, 0.0f);
      o.z = fmaxf(v[i].z - taur, 0.0f);
      o.w = fmaxf(v[i].w - taur, 0.0f);
      op[(size_t)i * 64] = o;
    }
  }
}

}  // namespace

extern "C" void kernel_launch(void* const* d_in, const int* in_sizes, int n_in,
                              void* d_out, int out_size, void* d_ws, size_t ws_size,
                              hipStream_t stream) {
  const float* x = (const float*)d_in[0];
  float* out = (float*)d_out;
  const int nrows = in_sizes[0] / K;       // 4,194,304
  const int ntiles = nrows / RPW;          // 65,536 (shape is fixed, divisible)

  const int threads = 256;                 // 4 waves/block
  int blocks = (ntiles + 3) / 4;
  if (blocks > 2048) blocks = 2048;        // grid-stride: 8 tiles per wave

  hipLaunchKernelGGL(sparsemax_kernel, dim3(blocks), dim3(threads), 0, stream,
                     x, out, ntiles);
}

// Round 3
// 210.777 us; speedup vs baseline: 1.3887x; 1.3887x over previous
//
#include <hip/hip_runtime.h>

namespace {

constexpr int K = 32;    // last-axis length
constexpr int RPW = 64;  // rows per wave (= wavefront size)

// Wave-cooperative sparsemax, register-pressure-minimized:
//   phase 1: coalesced float4 loads -> swizzled column-major LDS (v dies fast)
//   phase 2: lane l reads row l from LDS, sorts in regs, computes tau
//   phase 3: re-read originals from LDS in the coalesced a/b pattern,
//            fetch tau cross-lane, store coalesced.
// No two 32-float arrays are ever live at once -> no spills.
__global__ __launch_bounds__(256, 4)
void sparsemax_kernel(const float* __restrict__ x, float* __restrict__ out,
                      int ntiles) {
  __shared__ float lds[4][RPW * K];  // 8 KiB per wave, 32 KiB per block

  const int tid  = threadIdx.x;
  const int widx = tid >> 6;
  const int l    = tid & 63;
  float* __restrict__ wl = lds[widx];

  const int a  = l >> 3;   // 0..7 : sub-row selector
  const int b  = l & 7;    // 0..7 : col4 selector
  const int c0 = 4 * b;

  const int wave_global = blockIdx.x * 4 + widx;
  const int wave_stride = gridDim.x * 4;

  for (int t = wave_global; t < ntiles; t += wave_stride) {
    const size_t base_f4 = (size_t)t * (RPW * K / 4);
    const float4* __restrict__ xp =
        reinterpret_cast<const float4*>(x) + base_f4 + l;

    // Phase 1: load + stage. Element (row r, col c) lives at c*64 + (r^c)
    // (column-major, XOR swizzle -> 2 lanes/bank on every access = free).
    // Interleaved per-i so each float4 dies right after its 4 ds_writes.
#pragma unroll
    for (int i = 0; i < 8; ++i) {
      const float4 v = xp[(size_t)i * 64];
      const int r = 8 * i + a;
      wl[(c0 + 0) * 64 + (r ^ (c0 + 0))] = v.x;
      wl[(c0 + 1) * 64 + (r ^ (c0 + 1))] = v.y;
      wl[(c0 + 2) * 64 + (r ^ (c0 + 2))] = v.z;
      wl[(c0 + 3) * 64 + (r ^ (c0 + 3))] = v.w;
    }

    // Phase 2: lane l gathers its full row l (bank = (l^c)%32, 2-way, free).
    float rr[K];
#pragma unroll
    for (int c = 0; c < K; ++c) rr[c] = wl[c * 64 + (l ^ c)];

    // Bitonic sort, descending; 240 compare-exchanges, static indices.
#pragma unroll
    for (int kk = 2; kk <= K; kk <<= 1) {
#pragma unroll
      for (int j = kk >> 1; j > 0; j >>= 1) {
#pragma unroll
        for (int i = 0; i < K; ++i) {
          const int m = i ^ j;
          if (m > i) {
            const float p = rr[i], q = rr[m];
            const float mn = fminf(p, q);
            const float mx = fmaxf(p, q);
            if ((i & kk) == 0) { rr[i] = mx; rr[m] = mn; }
            else               { rr[i] = mn; rr[m] = mx; }
          }
        }
      }
    }

    // cumsum + support count: kz = #{ j : 1 + (j+1)*z_j - cumsum_j > 0 }.
    float csum = 0.0f;
    int kz = 0;
#pragma unroll
    for (int j = 0; j < K; ++j) {
      csum += rr[j];
      const float cond = 1.0f + (float)(j + 1) * rr[j] - csum;
      kz += (cond > 0.0f) ? 1 : 0;
      rr[j] = csum;  // rr now holds cumsum
    }

    // Gather cumsum[kz-1] with a static cndmask chain.
    float csel = rr[K - 1];
#pragma unroll
    for (int j = 0; j < K; ++j) csel = (kz == j + 1) ? rr[j] : csel;

    const float tau = (csel - 1.0f) / (float)kz;

    // Phase 3: re-read originals from LDS in the a/b pattern (addresses are
    // the same ones this lane wrote in phase 1; 2-way banks), combine with
    // cross-lane tau, store coalesced.
    float4* __restrict__ op = reinterpret_cast<float4*>(out) + base_f4 + l;
#pragma unroll
    for (int i = 0; i < 8; ++i) {
      const int r = 8 * i + a;
      const float taur = __shfl(tau, r);
      float4 o;
      o.x = fmaxf(wl[(c0 + 0) * 64 + (r ^ (c0 + 0))] - taur, 0.0f);
      o.y = fmaxf(wl[(c0 + 1) * 64 + (r ^ (c0 + 1))] - taur, 0.0f);
      o.z = fmaxf(wl[(c0 + 2) * 64 + (r ^ (c0 + 2))] - taur, 0.0f);
      o.w = fmaxf(wl[(c0 + 3) * 64 + (r ^ (c0 + 3))] - taur, 0.0f);
      op[(size_t)i * 64] = o;
    }
  }
}

}  // namespace

extern "C" void kernel_launch(void* const* d_in, const int* in_sizes, int n_in,
                              void* d_out, int out_size, void* d_ws, size_t ws_size,
                              hipStream_t stream) {
  const float* x = (const float*)d_in[0];
  float* out = (float*)d_out;
  const int nrows = in_sizes[0] / K;   // 4,194,304
  const int ntiles = nrows / RPW;      // 65,536

  const int threads = 256;             // 4 waves/block
  int blocks = (ntiles + 3) / 4;
  if (blocks > 2048) blocks = 2048;    // grid-stride: 8 tiles per wave

  hipLaunchKernelGGL(sparsemax_kernel, dim3(blocks), dim3(threads), 0, stream,
                     x, out, ntiles);
}